// Round 7
// baseline (102.369 us; speedup 1.0000x reference)
//
#include <hip/hip_runtime.h>
#include <hip/hip_bf16.h>

#define ROWS 1025   // B*N + 1
#define DD   128    // D
#define C3   384    // 3*D
#define BB   8
#define NN   128

#define NL2E  (-1.4426950408889634f)   // -log2(e)

__device__ __forceinline__ float bf2f(unsigned short u) {
    return __uint_as_float(((unsigned int)u) << 16);
}
__device__ __forceinline__ unsigned short f2bf(float f) {
    unsigned int i = __float_as_uint(f);            // finite data only
    return (unsigned short)((i + 0x7FFFu + ((i >> 16) & 1u)) >> 16);
}

// Pre-scaled packed gate tables, bf16x4 per (row, d):
//   GiP[row][d] = {-L*ir, -L*iz, -2L*in, 0}
//   GhP[row][d] = {-L*hr, -L*hz, -2L*hn, h}
// Block = 4 rows; 256 threads = (half: 0=Gi, 1=Gh) x (d 0..127).
// Weights read in ORIGINAL [384][128] layout: thread (half,d) streams rows
// W[d], W[128+d], W[256+d] contiguously along k (L1-resident lines).
__global__ __launch_bounds__(256, 4) void gtab_kernel(
    const float* __restrict__ h,
    const float* __restrict__ Wi, const float* __restrict__ Wh,
    const float* __restrict__ bi, const float* __restrict__ bh,
    unsigned short* __restrict__ GiP, unsigned short* __restrict__ GhP) {
    __shared__ float hs[4][DD];
    const int t  = threadIdx.x;
    const int r0 = blockIdx.x * 4;
    for (int idx = t; idx < 4 * DD; idx += 256) {
        const int r = idx >> 7, k = idx & (DD - 1);
        hs[r][k] = (r0 + r < ROWS) ? h[(size_t)(r0 + r) * DD + k] : 0.0f;
    }
    __syncthreads();

    const int half = t >> 7, d = t & (DD - 1);
    const float* __restrict__ W  = half ? Wh : Wi;
    const float* __restrict__ bb = half ? bh : bi;
    const float* __restrict__ w0 = W + (size_t)d * DD;
    const float* __restrict__ w1 = W + (size_t)(DD + d) * DD;
    const float* __restrict__ w2 = W + (size_t)(2 * DD + d) * DD;
    const float b0 = bb[d], b1 = bb[DD + d], b2 = bb[2 * DD + d];
    float a0[4] = {b0, b0, b0, b0};
    float a1[4] = {b1, b1, b1, b1};
    float a2[4] = {b2, b2, b2, b2};
    for (int k = 0; k < DD; k += 4) {
        const float4 v0 = *reinterpret_cast<const float4*>(w0 + k);
        const float4 v1 = *reinterpret_cast<const float4*>(w1 + k);
        const float4 v2 = *reinterpret_cast<const float4*>(w2 + k);
#pragma unroll
        for (int r = 0; r < 4; ++r) {
            const float h0 = hs[r][k], h1 = hs[r][k + 1];
            const float h2 = hs[r][k + 2], h3 = hs[r][k + 3];
            a0[r] += h0 * v0.x + h1 * v0.y + h2 * v0.z + h3 * v0.w;
            a1[r] += h0 * v1.x + h1 * v1.y + h2 * v1.z + h3 * v1.w;
            a2[r] += h0 * v2.x + h1 * v2.y + h2 * v2.z + h3 * v2.w;
        }
    }
    unsigned short* __restrict__ G = half ? GhP : GiP;
#pragma unroll
    for (int r = 0; r < 4; ++r) {
        if (r0 + r < ROWS) {
            ushort4 o;
            o.x = f2bf(a0[r] * NL2E);
            o.y = f2bf(a1[r] * NL2E);
            o.z = f2bf(a2[r] * (2.0f * NL2E));
            o.w = half ? f2bf(hs[r][d]) : (unsigned short)0;
            *reinterpret_cast<ushort4*>(G + (size_t)(r0 + r) * 512 + d * 4) = o;
        }
    }
}

// One block per (b,j); 512 threads = (ic 0..3) x (d 0..127); quarter ic sums 32 i's.
// Index LDS holds PRE-SHIFTED byte offsets (row*1024).
// XC=1: x=child, h=parent (bwd). XC=0: x=parent, h=child (fwd).
template<int XC, int WRITE_OUT>
__global__ __launch_bounds__(512, 4) void phase_kernel(
    const float* __restrict__ hin,
    const int* __restrict__ parent, const int* __restrict__ child,
    const unsigned short* __restrict__ GiP, const unsigned short* __restrict__ GhP,
    float* __restrict__ hout,
    const int* __restrict__ tgt, float* __restrict__ out) {
    const int bj = blockIdx.x;          // 0..1023
    const int t  = threadIdx.x;
    const int b  = bj >> 7, j = bj & (NN - 1);
    const size_t base = (size_t)b * NN * NN + j;          // + i*NN

    __shared__ int   pcs[2 * NN];       // interleaved {p<<10, c<<10}
    __shared__ float sacc[4][DD];
    if (t < NN)            pcs[2 * t]            = parent[base + (size_t)t * NN] << 10;
    else if (t < 2 * NN)   pcs[2 * (t - NN) + 1] = child [base + (size_t)(t - NN) * NN] << 10;
    __syncthreads();

    const int ic = t >> 7, d = t & (DD - 1);
    const unsigned int d8 = (unsigned int)d * 8u;
    const char* __restrict__ Gi8 = (const char*)GiP;
    const char* __restrict__ Gh8 = (const char*)GhP;
    float acc = 0.0f;
#pragma unroll 4
    for (int k = 0; k < 32; ++k) {
        const int  i  = ic * 32 + k;
        const int2 pc = *reinterpret_cast<const int2*>(&pcs[2 * i]);
        const unsigned int offx = (unsigned int)(XC ? pc.y : pc.x) + d8;
        const unsigned int offh = (unsigned int)(XC ? pc.x : pc.y) + d8;
        const uint2 ux = *reinterpret_cast<const uint2*>(Gi8 + offx);
        const uint2 uh = *reinterpret_cast<const uint2*>(Gh8 + offh);
        const float irs = __uint_as_float(ux.x << 16);
        const float izs = __uint_as_float(ux.x & 0xffff0000u);
        const float ins = __uint_as_float(ux.y << 16);
        const float hrs = __uint_as_float(uh.x << 16);
        const float hzs = __uint_as_float(uh.x & 0xffff0000u);
        const float hns = __uint_as_float(uh.y << 16);
        const float hv  = __uint_as_float(uh.y & 0xffff0000u);
        const float r = __builtin_amdgcn_rcpf(1.0f + __builtin_amdgcn_exp2f(irs + hrs));
        const float z = __builtin_amdgcn_rcpf(1.0f + __builtin_amdgcn_exp2f(izs + hzs));
        const float q = __builtin_amdgcn_rcpf(1.0f + __builtin_amdgcn_exp2f(ins + r * hns));
        const float n = 2.0f * q - 1.0f;
        acc += n + z * (hv - n);
    }
    sacc[ic][d] = acc;
    __syncthreads();

    if (ic == 0) {
        const float v   = sacc[0][d] + sacc[1][d] + sacc[2][d] + sacc[3][d];
        const int   row = 1 + bj;
        const float res = hin[(size_t)row * DD + d] + v;
        if (WRITE_OUT) {
#pragma unroll
            for (int bb = 0; bb < BB; ++bb)
                if (tgt[bb] == row) out[bb * DD + d] = res;
        } else {
            hout[(size_t)row * DD + d] = res;
        }
    } else if (ic == 1 && bj == 0 && !WRITE_OUT) {
        hout[d] = hin[d];                 // row 0 unchanged (tgt >= 1 always)
    }
}

extern "C" void kernel_launch(void* const* d_in, const int* in_sizes, int n_in,
                              void* d_out, int out_size, void* d_ws, size_t ws_size,
                              hipStream_t stream) {
    const float* hidden = (const float*)d_in[0];
    const int*   parent = (const int*)d_in[1];
    const int*   child  = (const int*)d_in[2];
    const int*   tgt    = (const int*)d_in[3];
    const float* Wif    = (const float*)d_in[4];
    const float* Whf    = (const float*)d_in[5];
    const float* bif    = (const float*)d_in[6];
    const float* bhf    = (const float*)d_in[7];
    const float* Wib    = (const float*)d_in[8];
    const float* Whb    = (const float*)d_in[9];
    const float* bib    = (const float*)d_in[10];
    const float* bhb    = (const float*)d_in[11];

    char* ws = (char*)d_ws;
    unsigned short* GiP = (unsigned short*)(ws);                  // 1025*512 bf16
    unsigned short* GhP = (unsigned short*)(ws + 1049600);        // 1025*512 bf16
    float*          h1  = (float*)(ws + 2099200);                 // 1025*128 f32
    float*          out = (float*)d_out;

    // Phase 1: bwd weights, x = child, h = parent
    gtab_kernel<<<257, 256, 0, stream>>>(hidden, Wib, Whb, bib, bhb, GiP, GhP);
    phase_kernel<1, 0><<<BB * NN, 512, 0, stream>>>(hidden, parent, child, GiP, GhP, h1, nullptr, nullptr);
    // Phase 2: fwd weights, x = parent, h = child; tgt gather fused
    gtab_kernel<<<257, 256, 0, stream>>>(h1, Wif, Whf, bif, bhf, GiP, GhP);
    phase_kernel<0, 1><<<BB * NN, 512, 0, stream>>>(h1, parent, child, GiP, GhP, nullptr, tgt, out);
}